// Round 5
// baseline (32.258 us; speedup 1.0000x reference)
//
#include <hip/hip_runtime.h>
#include <float.h>
#include <math.h>

#define BB 8
#define PP 4096
#define QB 128      // queries per block
#define QPL 2       // queries per lane (2 * 64 = 128)
#define SEGW 256    // neighbors per wave (4096 / 16 waves)
#define NBLK 512    // (dir, cloud, qgroup) blocks -> 2 per CU

// One block = (dir, cloud, qgroup of 128 queries) vs ALL 4096 neighbors.
// t = |c|^2/2 - a.c is argmin-equivalent to d^2; d^2 = |a|^2 + 2*min_t.
__global__ __launch_bounds__(1024) void chamfer_main(
    const float* __restrict__ y1, const float* __restrict__ y2,
    float* __restrict__ partial)
{
    __shared__ float4 nb[PP];     // 64 KB: (x, y, z, |c|^2/2); pmin aliases it later
    __shared__ float ssum[2];

    const int bid   = blockIdx.x;
    const int qg    = bid & 31;
    const int cloud = (bid >> 5) & 7;
    const int dir   = bid >> 8;

    const float* src = (dir == 0) ? y1 : y2;
    const float* tgt = (dir == 0) ? y2 : y1;
    const float* __restrict__ tgt_base = tgt + (size_t)cloud * PP * 3;
    const float* __restrict__ src_base = src + ((size_t)cloud * PP + (size_t)qg * QB) * 3;

    const int tid  = threadIdx.x;
    const int lane = tid & 63;
    const int w    = tid >> 6;

    // Stage the whole target cloud into LDS as (x,y,z,h), 4 per thread, coalesced.
    #pragma unroll
    for (int r = 0; r < 4; ++r) {
        const int idx = tid + r * 1024;
        const float* g = tgt_base + (size_t)idx * 3;
        const float x = g[0], yv = g[1], z = g[2];
        nb[idx] = make_float4(x, yv, z, 0.5f * (x * x + yv * yv + z * z));
    }

    // Each lane owns 2 query points (pre-negated for the FMA chain).
    float nax[QPL], nay[QPL], naz[QPL], acc[QPL];
    #pragma unroll
    for (int k = 0; k < QPL; ++k) {
        const float* q = src_base + (size_t)(lane + k * 64) * 3;
        nax[k] = -q[0]; nay[k] = -q[1]; naz[k] = -q[2];
        acc[k] = FLT_MAX;
    }
    __syncthreads();

    // Main loop over this wave's 256-neighbor segment, 1-deep register prefetch.
    const float4* __restrict__ base = &nb[w * SEGW];
    float4 c0 = base[0], c1 = base[1], c2 = base[2], c3 = base[3];

#define CHAMFER_STEP                                                              \
    do {                                                                          \
        _Pragma("unroll")                                                         \
        for (int k = 0; k < QPL; ++k) {                                           \
            float t0 = fmaf(nax[k], c0.x, fmaf(nay[k], c0.y, fmaf(naz[k], c0.z, c0.w))); \
            float t1 = fmaf(nax[k], c1.x, fmaf(nay[k], c1.y, fmaf(naz[k], c1.z, c1.w))); \
            acc[k] = fminf(fminf(t0, t1), acc[k]);                                \
            float t2 = fmaf(nax[k], c2.x, fmaf(nay[k], c2.y, fmaf(naz[k], c2.z, c2.w))); \
            float t3 = fmaf(nax[k], c3.x, fmaf(nay[k], c3.y, fmaf(naz[k], c3.z, c3.w))); \
            acc[k] = fminf(fminf(t2, t3), acc[k]);                                \
        }                                                                         \
    } while (0)

    for (int i = 4; i < SEGW; i += 4) {
        float4 d0 = base[i + 0];
        float4 d1 = base[i + 1];
        float4 d2 = base[i + 2];
        float4 d3 = base[i + 3];
        CHAMFER_STEP;
        c0 = d0; c1 = d1; c2 = d2; c3 = d3;
    }
    CHAMFER_STEP;
#undef CHAMFER_STEP

    // All waves done reading nb -> reuse its storage for the 8 KB pmin scratch.
    __syncthreads();
    float* pmin = reinterpret_cast<float*>(nb);   // [16][QB]
    #pragma unroll
    for (int k = 0; k < QPL; ++k)
        pmin[w * QB + lane + k * 64] = acc[k];
    __syncthreads();

    // Threads 0..127: combine 16 waves' mins, form distance, block-sum.
    if (tid < QB) {
        float m = pmin[tid];
        #pragma unroll
        for (int ww = 1; ww < 16; ++ww)
            m = fminf(m, pmin[ww * QB + tid]);
        const float* qv = src_base + (size_t)tid * 3;  // L1-hot reload
        const float aa = qv[0] * qv[0] + qv[1] * qv[1] + qv[2] * qv[2];
        float d = sqrtf(fmaxf(0.0f, fmaf(2.0f, m, aa)));

        #pragma unroll
        for (int off = 32; off > 0; off >>= 1)
            d += __shfl_down(d, off);
        if ((tid & 63) == 0)
            ssum[tid >> 6] = d;
    }
    __syncthreads();
    if (tid == 0)
        partial[bid] = ssum[0] + ssum[1];
}

// Sum 512 block partials, normalize by B*P (gives d1 + d2).
__global__ __launch_bounds__(512) void chamfer_final(
    const float* __restrict__ partial, float* __restrict__ out)
{
    __shared__ float ssum[8];
    const int tid = threadIdx.x;
    float v = partial[tid];
    #pragma unroll
    for (int off = 32; off > 0; off >>= 1)
        v += __shfl_down(v, off);
    if ((tid & 63) == 0)
        ssum[tid >> 6] = v;
    __syncthreads();
    if (tid == 0) {
        float s = 0.0f;
        #pragma unroll
        for (int i = 0; i < 8; ++i) s += ssum[i];
        out[0] = s * (1.0f / (float)(BB * PP));
    }
}

extern "C" void kernel_launch(void* const* d_in, const int* in_sizes, int n_in,
                              void* d_out, int out_size, void* d_ws, size_t ws_size,
                              hipStream_t stream) {
    const float* y1 = (const float*)d_in[0];
    const float* y2 = (const float*)d_in[1];
    float* partial = (float*)d_ws;    // 512 floats of scratch
    float* out     = (float*)d_out;

    chamfer_main<<<NBLK, 1024, 0, stream>>>(y1, y2, partial);
    chamfer_final<<<1, 512, 0, stream>>>(partial, out);
}

// Round 6
// 17.960 us; speedup vs baseline: 1.7960x; 1.7960x over previous
//
#include <hip/hip_runtime.h>
#include <float.h>
#include <math.h>

#define BB 8
#define PP 4096

typedef __attribute__((ext_vector_type(8))) short bf16x8;
typedef __attribute__((ext_vector_type(16))) float f32x16;

__device__ __forceinline__ unsigned int f2bf(float f) {
    unsigned int u = __float_as_uint(f);
    return (u + 0x7FFFu + ((u >> 16) & 1u)) >> 16;   // RNE bf16
}
__device__ __forceinline__ float bf2f(unsigned int h) {
    return __uint_as_float(h << 16);
}
__device__ __forceinline__ float min3f(float a, float b, float c) {
    return fminf(fminf(a, b), c);                    // fuses to v_min3_f32
}

// One block = (dir, cloud, qgroup of 256 queries) vs all 4096 neighbors.
// MFMA computes t_ji = h_j - a_i.c_j directly (split-precision bf16 packed in K);
// d^2 = |a|^2 + 2*min_j t.  D[j,i]: col=lane&31 (query), rows over regs/lane-half.
__global__ __launch_bounds__(1024) void chamfer_mfma(
    const float* __restrict__ y1, const float* __restrict__ y2,
    float* __restrict__ partial)
{
    __shared__ uint4 fbuf[64 * 64];   // 64 KB: A-frags for 64 neighbor tiles (half cloud)

    const int bid   = blockIdx.x;
    const int qg    = bid & 15;
    const int cloud = (bid >> 4) & 7;
    const int dir   = bid >> 7;

    const float* src = (dir == 0) ? y1 : y2;
    const float* tgt = (dir == 0) ? y2 : y1;
    const float* __restrict__ tgt_base = tgt + (size_t)cloud * PP * 3;
    const float* __restrict__ src_base = src + ((size_t)cloud * PP + (size_t)qg * 256) * 3;

    const int tid  = threadIdx.x;
    const int lane = tid & 63;
    const int w    = tid >> 6;
    const int ig   = w & 1;     // which 4 itiles (128 queries) this wave owns
    const int jg   = w >> 1;    // which 8 jtiles per 64-tile half this wave owns

    // ---- B-frags (queries), built once in registers ----
    // lane<32 (k0..7):  [nahix,nahiy,nahiz, nalox,naloy,naloz, nahix,nahiy]
    // lane>=32 (k8..15):[nahiz, 1.0, 1.0, 0,0,0,0,0]
    bf16x8 bfrag[4];
    #pragma unroll
    for (int t = 0; t < 4; ++t) {
        const int ql = (ig * 4 + t) * 32 + (lane & 31);
        const float ax = src_base[ql * 3 + 0];
        const float ay = src_base[ql * 3 + 1];
        const float az = src_base[ql * 3 + 2];
        const unsigned int hx = f2bf(-ax), hy = f2bf(-ay), hz = f2bf(-az);
        const unsigned int lx = f2bf(-ax - bf2f(hx));
        const unsigned int ly = f2bf(-ay - bf2f(hy));
        const unsigned int lz = f2bf(-az - bf2f(hz));
        uint4 bb;
        if (lane < 32) {
            bb.x = hx | (hy << 16);
            bb.y = hz | (lx << 16);
            bb.z = ly | (lz << 16);
            bb.w = hx | (hy << 16);
        } else {
            bb.x = hz | (0x3F80u << 16);   // k8 = nahiz, k9 = 1.0
            bb.y = 0x3F80u;                // k10 = 1.0, k11 = 0
            bb.z = 0u;
            bb.w = 0u;
        }
        bfrag[t] = *reinterpret_cast<bf16x8*>(&bb);
    }

    float m[4][4];
    #pragma unroll
    for (int t = 0; t < 4; ++t)
        #pragma unroll
        for (int r = 0; r < 4; ++r)
            m[t][r] = FLT_MAX;

    f32x16 zc;
    #pragma unroll
    for (int r = 0; r < 16; ++r) zc[r] = 0.0f;

    for (int half = 0; half < 2; ++half) {
        // ---- Build A-frags for neighbors half*2048 .. +2047 ----
        // A lane<32 (k0..7):  [chix,chiy,chiz, chix,chiy,chiz, clox,cloy]
        // A lane>=32 (k8..15):[cloz, h_hi, h_lo, 0,0,0,0,0]
        #pragma unroll
        for (int rep = 0; rep < 2; ++rep) {
            const int nl = rep * 1024 + tid;            // 0..2047 within half
            const int n  = half * 2048 + nl;
            const float cx = tgt_base[n * 3 + 0];
            const float cy = tgt_base[n * 3 + 1];
            const float cz = tgt_base[n * 3 + 2];
            const unsigned int chx = f2bf(cx), chy = f2bf(cy), chz = f2bf(cz);
            const unsigned int clx = f2bf(cx - bf2f(chx));
            const unsigned int cly = f2bf(cy - bf2f(chy));
            const unsigned int clz = f2bf(cz - bf2f(chz));
            const float hh = 0.5f * (cx * cx + cy * cy + cz * cz);
            const unsigned int hhi = f2bf(hh);
            const unsigned int hlo = f2bf(hh - bf2f(hhi));
            const int tile = nl >> 5, r = nl & 31;
            uint4 lof, hif;
            lof.x = chx | (chy << 16);
            lof.y = chz | (chx << 16);
            lof.z = chy | (chz << 16);
            lof.w = clx | (cly << 16);
            hif.x = clz | (hhi << 16);
            hif.y = hlo;
            hif.z = 0u;
            hif.w = 0u;
            fbuf[tile * 64 + r]      = lof;
            fbuf[tile * 64 + 32 + r] = hif;
        }
        __syncthreads();

        // ---- Main loop: 8 jtiles x 4 itiles of MFMA + running min ----
        for (int jt = jg * 8; jt < jg * 8 + 8; ++jt) {
            const bf16x8 af = *reinterpret_cast<const bf16x8*>(&fbuf[jt * 64 + lane]);
            #pragma unroll
            for (int t = 0; t < 4; ++t) {
                f32x16 acc = __builtin_amdgcn_mfma_f32_32x32x16_bf16(af, bfrag[t], zc, 0, 0, 0);
                m[t][0] = min3f(m[t][0], acc[0], acc[4]);
                m[t][1] = min3f(m[t][1], acc[1], acc[5]);
                m[t][2] = min3f(m[t][2], acc[2], acc[6]);
                m[t][3] = min3f(m[t][3], acc[3], acc[7]);
                m[t][0] = min3f(m[t][0], acc[8], acc[12]);
                m[t][1] = min3f(m[t][1], acc[9], acc[13]);
                m[t][2] = min3f(m[t][2], acc[10], acc[14]);
                m[t][3] = min3f(m[t][3], acc[11], acc[15]);
            }
        }
        __syncthreads();   // frags fully consumed before rebuild / reuse
    }

    // ---- Epilogue: cross-half-lane min, cross-wave min, distance, block sum ----
    float* pmin = reinterpret_cast<float*>(fbuf);   // [8][256], aliases fbuf
    float* ssum = pmin + 2048;                      // 4 floats
    #pragma unroll
    for (int t = 0; t < 4; ++t) {
        float mm = fminf(fminf(m[t][0], m[t][1]), fminf(m[t][2], m[t][3]));
        mm = fminf(mm, __shfl_xor(mm, 32));
        if (lane < 32)
            pmin[jg * 256 + (ig * 4 + t) * 32 + (lane & 31)] = mm;
    }
    __syncthreads();
    if (tid < 256) {
        float v = pmin[tid];
        #pragma unroll
        for (int g = 1; g < 8; ++g)
            v = fminf(v, pmin[g * 256 + tid]);
        const float ax = src_base[tid * 3 + 0];
        const float ay = src_base[tid * 3 + 1];
        const float az = src_base[tid * 3 + 2];
        const float aa = ax * ax + ay * ay + az * az;
        float d = sqrtf(fmaxf(0.0f, fmaf(2.0f, v, aa)));
        #pragma unroll
        for (int off = 32; off > 0; off >>= 1)
            d += __shfl_down(d, off);
        if ((tid & 63) == 0)
            ssum[tid >> 6] = d;
    }
    __syncthreads();
    if (tid == 0)
        partial[bid] = ssum[0] + ssum[1] + ssum[2] + ssum[3];
}

// Sum 256 block partials, normalize by B*P (gives d1 + d2).
__global__ __launch_bounds__(256) void chamfer_final(
    const float* __restrict__ partial, float* __restrict__ out)
{
    __shared__ float ssum[4];
    const int tid = threadIdx.x;
    float v = partial[tid];
    #pragma unroll
    for (int off = 32; off > 0; off >>= 1)
        v += __shfl_down(v, off);
    if ((tid & 63) == 0)
        ssum[tid >> 6] = v;
    __syncthreads();
    if (tid == 0)
        out[0] = (ssum[0] + ssum[1] + ssum[2] + ssum[3]) * (1.0f / (float)(BB * PP));
}

extern "C" void kernel_launch(void* const* d_in, const int* in_sizes, int n_in,
                              void* d_out, int out_size, void* d_ws, size_t ws_size,
                              hipStream_t stream) {
    const float* y1 = (const float*)d_in[0];
    const float* y2 = (const float*)d_in[1];
    float* partial = (float*)d_ws;    // 256 floats of scratch
    float* out     = (float*)d_out;

    chamfer_mfma<<<256, 1024, 0, stream>>>(y1, y2, partial);
    chamfer_final<<<1, 256, 0, stream>>>(partial, out);
}